// Round 6
// baseline (256.764 us; speedup 1.0000x reference)
//
#include <hip/hip_runtime.h>
#include <hip/hip_bf16.h>
#include <stdint.h>

#define BATCH 4
#define SEQ   2048
#define EMB   1024
#define ADIM  1024

typedef __attribute__((ext_vector_type(8))) short  short8;
typedef __attribute__((ext_vector_type(4))) float  float4v;

static __device__ __forceinline__ unsigned short f2bf(float f) {
    unsigned int u = __float_as_uint(f);
    u += 0x7FFFu + ((u >> 16) & 1u);   // RNE (finite inputs)
    return (unsigned short)(u >> 16);
}

static __device__ __forceinline__ uint2 pack4(float4v v) {
    uint2 r;
    r.x = (unsigned)f2bf(v.x) | ((unsigned)f2bf(v.y) << 16);
    r.y = (unsigned)f2bf(v.z) | ((unsigned)f2bf(v.w) << 16);
    return r;
}

// async global->LDS, 16B per lane. LDS dest is wave-uniform base + lane*16.
static __device__ __forceinline__ void gload16(const void* g, void* l) {
    __builtin_amdgcn_global_load_lds(
        (const __attribute__((address_space(1))) void*)g,
        (__attribute__((address_space(3))) void*)l, 16, 0, 0);
}

// ---- cvt: X -> Xb (bf16), Wv -> Wvb (bf16), zero rowsum. One launch. ----
__global__ __launch_bounds__(256) void cvt_all_kernel(
    const float* __restrict__ X,  const float* __restrict__ Wv,
    unsigned short* __restrict__ Xb, unsigned short* __restrict__ Wvb,
    float* __restrict__ rowsum)
{
    const int bI = blockIdx.x;
    if (bI >= 4608) {   // zero 32 KB rowsum
        const int i = ((bI - 4608) * 256 + threadIdx.x) * 4;
        *(float4v*)(rowsum + i) = float4v{0.f, 0.f, 0.f, 0.f};
        return;
    }
    const float* src; unsigned short* dst; int off;
    if (bI < 4096) { src = X;  dst = Xb;  off = bI; }
    else           { src = Wv; dst = Wvb; off = bI - 4096; }
    const int i = (off * 256 + threadIdx.x) * 8;
    float4v a = *(const float4v*)(src + i);
    float4v b = *(const float4v*)(src + i + 4);
    uint2 pa = pack4(a), pb = pack4(b);
    uint4 o; o.x = pa.x; o.y = pa.y; o.z = pb.x; o.w = pb.y;
    *(uint4*)(dst + i) = o;
}

// ---- transpose-convert: W fp32 [a][e] -> WT bf16 [e][a], 64x64 tiles ----
__global__ __launch_bounds__(256) void tcvt_kernel(
    const float* __restrict__ Wq, const float* __restrict__ Wk,
    unsigned short* __restrict__ WqT, unsigned short* __restrict__ WkT)
{
    __shared__ unsigned short T[64][72];
    const int z    = blockIdx.x >> 8;      // 0: Wq, 1: Wk
    const int tile = blockIdx.x & 255;
    const int ti = tile >> 4;              // a-tile
    const int tj = tile & 15;              // e-tile
    const float* W = z ? Wk : Wq;
    unsigned short* WT = z ? WkT : WqT;
    const int t  = threadIdx.x;
    const int r  = t >> 2;                 // 0..63
    const int c  = (t & 3) << 4;           // 0,16,32,48

    const float* src = W + (size_t)(ti * 64 + r) * EMB + tj * 64 + c;
    #pragma unroll
    for (int u = 0; u < 4; ++u) {
        float4v v = *(const float4v*)(src + 4 * u);
        uint2 p = pack4(v);
        *(uint2*)&T[r][c + 4 * u] = p;
    }
    __syncthreads();
    unsigned short tmp[16];
    #pragma unroll
    for (int u = 0; u < 16; ++u) tmp[u] = T[c + u][r];
    unsigned short* dst = WT + (size_t)(tj * 64 + r) * EMB + ti * 64 + c;
    *(uint4*)(dst)     = *(uint4*)&tmp[0];
    *(uint4*)(dst + 8) = *(uint4*)&tmp[8];
}

// C(128x128) = A[m0..+128, :] * B[n0..+128, :]^T, bf16, fp32 acc.
// 3-stage pipeline, BK=32/stage, vmcnt(8), raw barriers (no vmcnt(0) in loop).
static __device__ __forceinline__ void gemm_core(
    const unsigned short* __restrict__ A, const unsigned short* __restrict__ B,
    int lda, int ldb, int m0, int n0, int kend,
    unsigned short* As, unsigned short* Bs, float4v acc[4][4])
{
    const int tid  = threadIdx.x;
    const int r    = tid >> 2;
    const int c8   = (tid & 3) << 3;
    const int lane = tid & 63;
    const int wave = tid >> 6;
    const int quad = lane >> 4;
    const int l16  = lane & 15;
    const int wm   = (wave >> 1) << 6;
    const int wn   = (wave & 1) << 6;

    const unsigned short* Ag = A + (size_t)(m0 + r) * lda + c8;
    const unsigned short* Bg = B + (size_t)(n0 + r) * ldb + c8;
    unsigned short* Al = As + tid * 8;
    unsigned short* Bl = Bs + tid * 8;
    const int niter = kend >> 5;

    #define ISSUE(k0, st) do { \
        unsigned short* al_ = Al + (st) * 4096; \
        unsigned short* bl_ = Bl + (st) * 4096; \
        gload16(Ag + (k0),                    al_); \
        gload16(Ag + (k0) + (size_t)64 * lda, al_ + 2048); \
        gload16(Bg + (k0),                    bl_); \
        gload16(Bg + (k0) + (size_t)64 * ldb, bl_ + 2048); \
    } while (0)

    ISSUE(0, 0);
    ISSUE(32, 1);

    int ci = 0, ii = 2;
    for (int it = 0; it < niter; ++it) {
        const int knext = (it + 2 < niter) ? ((it + 2) << 5) : 0;
        ISSUE(knext, ii);
        asm volatile("s_waitcnt vmcnt(8)" ::: "memory");
        asm volatile("s_barrier" ::: "memory");

        const unsigned short* Ah = As + ci * 4096;
        const unsigned short* Bh = Bs + ci * 4096;
        short8 af[4], bfr[4];
        #pragma unroll
        for (int i = 0; i < 4; ++i)
            af[i] = *(const short8*)&Ah[(wm + 16 * i + l16) * 32 + quad * 8];
        #pragma unroll
        for (int j = 0; j < 4; ++j)
            bfr[j] = *(const short8*)&Bh[(wn + 16 * j + l16) * 32 + quad * 8];
        #pragma unroll
        for (int i = 0; i < 4; ++i)
            #pragma unroll
            for (int j = 0; j < 4; ++j)
                acc[i][j] = __builtin_amdgcn_mfma_f32_16x16x32_bf16(af[i], bfr[j], acc[i][j], 0, 0, 0);

        asm volatile("s_barrier" ::: "memory");
        ci = (ci == 2) ? 0 : ci + 1;
        ii = (ii == 2) ? 0 : ii + 1;
    }
    asm volatile("s_waitcnt vmcnt(0)" ::: "memory");
    #undef ISSUE
}

#define DECL_TILE_IDX() \
    const int lane = threadIdx.x & 63; \
    const int wave = threadIdx.x >> 6; \
    const int quad = lane >> 4; \
    const int l16  = lane & 15; \
    const int wm   = (wave >> 1) << 6; \
    const int wn   = (wave & 1) << 6;

// ---- Mt = (Wq^T Wk)^T * (1/sqrt(A)): gemm(WkT, WqT) contracting over a ----
__global__ __launch_bounds__(256, 3) void m_kernel(
    const unsigned short* __restrict__ WkT, const unsigned short* __restrict__ WqT,
    unsigned short* __restrict__ Mt)
{
    __shared__ __align__(16) unsigned short As[3 * 128 * 32];
    __shared__ __align__(16) unsigned short Bs[3 * 128 * 32];
    const int m0 = (blockIdx.x >> 3) << 7;   // e' tile
    const int n0 = (blockIdx.x & 7) << 7;    // e  tile

    float4v acc[4][4];
    #pragma unroll
    for (int i = 0; i < 4; ++i)
        #pragma unroll
        for (int j = 0; j < 4; ++j)
            acc[i][j] = float4v{0.f, 0.f, 0.f, 0.f};

    gemm_core(WkT, WqT, EMB, EMB, m0, n0, EMB, As, Bs, acc);

    DECL_TILE_IDX();
    const float scale = 0.03125f;  // 1/sqrt(1024), folded here
    #pragma unroll
    for (int i = 0; i < 4; ++i)
        #pragma unroll
        for (int j = 0; j < 4; ++j)
            #pragma unroll
            for (int rr = 0; rr < 4; ++rr) {
                const int row = m0 + wm + 16 * i + quad * 4 + rr;
                const int col = n0 + wn + 16 * j + l16;
                Mt[(size_t)row * EMB + col] = f2bf(acc[i][j][rr] * scale);
            }
}

// ---- Q' = Xb Mt^T (z=0) and V = Xb Wv^T -> Vtb transposed (z=1).
// XCD swizzle: low 3 bits = m-subtile so W/Mt tiles stay L2-resident per XCD. ----
__global__ __launch_bounds__(256, 3) void qv_kernel(
    const unsigned short* __restrict__ Xb, const unsigned short* __restrict__ Mt,
    const unsigned short* __restrict__ Wvb,
    unsigned short* __restrict__ Qpb, unsigned short* __restrict__ Vtb)
{
    __shared__ __align__(16) unsigned short As[3 * 128 * 32];
    __shared__ __align__(16) unsigned short Bs[3 * 128 * 32];
    const int idx   = blockIdx.x;          // 0..1023
    const int mlow  = idx & 7;
    const int n0    = ((idx >> 3) & 7) << 7;
    const int mhigh = (idx >> 6) & 7;
    const int z     = idx >> 9;
    const int m0    = ((mhigh << 3) | mlow) << 7;
    const unsigned short* W = (z == 0) ? Mt : Wvb;

    float4v acc[4][4];
    #pragma unroll
    for (int i = 0; i < 4; ++i)
        #pragma unroll
        for (int j = 0; j < 4; ++j)
            acc[i][j] = float4v{0.f, 0.f, 0.f, 0.f};

    gemm_core(Xb, W, EMB, EMB, m0, n0, EMB, As, Bs, acc);

    DECL_TILE_IDX();
    #pragma unroll
    for (int i = 0; i < 4; ++i)
        #pragma unroll
        for (int j = 0; j < 4; ++j)
            #pragma unroll
            for (int rr = 0; rr < 4; ++rr) {
                const int row = m0 + wm + 16 * i + quad * 4 + rr;
                const int col = n0 + wn + 16 * j + l16;
                const unsigned short v = f2bf(acc[i][j][rr]);
                if (z == 0) Qpb[(size_t)row * ADIM + col] = v;
                else {
                    const int bb = row >> 11;
                    const int l  = row & (SEQ - 1);
                    Vtb[((size_t)(bb * ADIM + col) << 11) + l] = v;
                }
            }
}

// ---- E = exp(Q' Xb^T) (scale pre-folded into Mt), causal, + rowsum atomics ----
__global__ __launch_bounds__(256, 3) void s_kernel(
    const unsigned short* __restrict__ Qpb, const unsigned short* __restrict__ Xb,
    unsigned short* __restrict__ E, float* __restrict__ rowsum)
{
    const int idx = blockIdx.x;
    const int b   = idx & 3;
    const int tri = idx >> 2;
    int qt = 0;
    while (((qt + 1) * (qt + 2)) / 2 <= tri) ++qt;
    const int kt = tri - (qt * (qt + 1)) / 2;
    const int q0 = qt << 7;
    const int k0 = kt << 7;

    __shared__ __align__(16) unsigned short As[3 * 128 * 32];
    __shared__ __align__(16) unsigned short Bs[3 * 128 * 32];

    float4v acc[4][4];
    #pragma unroll
    for (int i = 0; i < 4; ++i)
        #pragma unroll
        for (int j = 0; j < 4; ++j)
            acc[i][j] = float4v{0.f, 0.f, 0.f, 0.f};

    gemm_core(Qpb + (size_t)b * SEQ * ADIM, Xb + (size_t)b * SEQ * EMB,
              ADIM, EMB, q0, k0, EMB, As, Bs, acc);

    unsigned short* Eb = E + (size_t)b * SEQ * SEQ;
    float* rsb = rowsum + (size_t)b * SEQ;
    DECL_TILE_IDX();
    #pragma unroll
    for (int i = 0; i < 4; ++i)
        #pragma unroll
        for (int rr = 0; rr < 4; ++rr) {
            const int row = q0 + wm + 16 * i + quad * 4 + rr;
            float s = 0.f;
            #pragma unroll
            for (int j = 0; j < 4; ++j) {
                const int col = k0 + wn + 16 * j + l16;
                float e = (col <= row) ? __expf(acc[i][j][rr]) : 0.f;
                s += e;
                Eb[(size_t)row * SEQ + col] = f2bf(e);
            }
            s += __shfl_xor(s, 1);
            s += __shfl_xor(s, 2);
            s += __shfl_xor(s, 4);
            s += __shfl_xor(s, 8);
            if (l16 == 0) atomicAdd(&rsb[row], s);
        }
}

// ---- O = (E V) / rowsum, heavy-first (LPT) ordering, causal K bound ----
__global__ __launch_bounds__(256, 3) void pv_kernel(
    const unsigned short* __restrict__ E, const unsigned short* __restrict__ Vtb,
    const float* __restrict__ rowsum, float* __restrict__ out)
{
    const int idx = blockIdx.x;
    const int t   = 15 - (idx >> 5);
    const int rem = idx & 31;
    const int b   = rem >> 3;
    const int a0  = (rem & 7) << 7;
    const int q0  = t << 7;

    __shared__ __align__(16) unsigned short As[3 * 128 * 32];
    __shared__ __align__(16) unsigned short Bs[3 * 128 * 32];

    float4v acc[4][4];
    #pragma unroll
    for (int i = 0; i < 4; ++i)
        #pragma unroll
        for (int j = 0; j < 4; ++j)
            acc[i][j] = float4v{0.f, 0.f, 0.f, 0.f};

    gemm_core(E + (size_t)b * SEQ * SEQ, Vtb + (size_t)b * ADIM * SEQ,
              SEQ, SEQ, q0, a0, q0 + 128, As, Bs, acc);

    float* ob = out + (size_t)b * SEQ * ADIM;
    const float* rsb = rowsum + (size_t)b * SEQ;
    DECL_TILE_IDX();
    #pragma unroll
    for (int i = 0; i < 4; ++i)
        #pragma unroll
        for (int rr = 0; rr < 4; ++rr) {
            const int row = q0 + wm + 16 * i + quad * 4 + rr;
            const float inv = 1.0f / rsb[row];
            #pragma unroll
            for (int j = 0; j < 4; ++j) {
                const int col = a0 + wn + 16 * j + l16;
                ob[(size_t)row * ADIM + col] = acc[i][j][rr] * inv;
            }
        }
}

extern "C" void kernel_launch(void* const* d_in, const int* in_sizes, int n_in,
                              void* d_out, int out_size, void* d_ws, size_t ws_size,
                              hipStream_t stream)
{
    // setup_inputs order: embedded, W_K, W_Q, W_V
    const float* X  = (const float*)d_in[0];
    const float* Wk = (const float*)d_in[1];
    const float* Wq = (const float*)d_in[2];
    const float* Wv = (const float*)d_in[3];
    float* out = (float*)d_out;

    const size_t MB = 1024 * 1024;
    char* ws = (char*)d_ws;
    unsigned short* Xb  = (unsigned short*)(ws);             // [0,16) MB
    unsigned short* Wvb = (unsigned short*)(ws + 16 * MB);   // [16,18)
    unsigned short* WqT = (unsigned short*)(ws + 18 * MB);   // [18,20)
    unsigned short* WkT = (unsigned short*)(ws + 20 * MB);   // [20,22)
    unsigned short* Mt  = (unsigned short*)(ws + 22 * MB);   // [22,24)
    unsigned short* Qpb = (unsigned short*)(ws + 24 * MB);   // [24,40)
    unsigned short* E   = (unsigned short*)(ws + 40 * MB);   // [40,72)
    unsigned short* Vtb = (unsigned short*)(ws + 72 * MB);   // [72,88)
    float*          rowsum = (float*)(ws + 88 * MB);         // 32 KB

    hipLaunchKernelGGL(cvt_all_kernel, dim3(4616), dim3(256), 0, stream,
                       X, Wv, Xb, Wvb, rowsum);
    hipLaunchKernelGGL(tcvt_kernel, dim3(512), dim3(256), 0, stream,
                       Wq, Wk, WqT, WkT);
    hipLaunchKernelGGL(m_kernel, dim3(64), dim3(256), 0, stream, WkT, WqT, Mt);
    hipLaunchKernelGGL(qv_kernel, dim3(1024), dim3(256), 0, stream,
                       Xb, Mt, Wvb, Qpb, Vtb);
    hipLaunchKernelGGL(s_kernel, dim3(4 * 136), dim3(256), 0, stream, Qpb, Xb, E, rowsum);
    hipLaunchKernelGGL(pv_kernel, dim3(512), dim3(256), 0, stream, E, Vtb, rowsum, out);
}

// Round 7
// 240.211 us; speedup vs baseline: 1.0689x; 1.0689x over previous
//
#include <hip/hip_runtime.h>
#include <hip/hip_bf16.h>
#include <stdint.h>

#define BATCH 4
#define SEQ   2048
#define EMB   1024
#define ADIM  1024

typedef __attribute__((ext_vector_type(8))) short  short8;
typedef __attribute__((ext_vector_type(4))) float  float4v;

static __device__ __forceinline__ unsigned short f2bf(float f) {
    unsigned int u = __float_as_uint(f);
    u += 0x7FFFu + ((u >> 16) & 1u);   // RNE (finite inputs)
    return (unsigned short)(u >> 16);
}

static __device__ __forceinline__ uint2 pack4(float4v v) {
    uint2 r;
    r.x = (unsigned)f2bf(v.x) | ((unsigned)f2bf(v.y) << 16);
    r.y = (unsigned)f2bf(v.z) | ((unsigned)f2bf(v.w) << 16);
    return r;
}

// async global->LDS, 16B per lane. LDS dest is wave-uniform base + lane*16.
static __device__ __forceinline__ void gload16(const void* g, void* l) {
    __builtin_amdgcn_global_load_lds(
        (const __attribute__((address_space(1))) void*)g,
        (__attribute__((address_space(3))) void*)l, 16, 0, 0);
}

// ---- fused prep: X->Xb, Wv->Wvb, zero rowsum, transpose-convert Wq/Wk ----
__global__ __launch_bounds__(256) void prep_kernel(
    const float* __restrict__ X,  const float* __restrict__ Wv,
    const float* __restrict__ Wq, const float* __restrict__ Wk,
    unsigned short* __restrict__ Xb, unsigned short* __restrict__ Wvb,
    unsigned short* __restrict__ WqT, unsigned short* __restrict__ WkT,
    float* __restrict__ rowsum)
{
    __shared__ unsigned short T[64][72];
    const int bI = blockIdx.x;
    if (bI < 4608) {              // straight convert
        const float* src; unsigned short* dst; int off;
        if (bI < 4096) { src = X;  dst = Xb;  off = bI; }
        else           { src = Wv; dst = Wvb; off = bI - 4096; }
        const int i = (off * 256 + threadIdx.x) * 8;
        float4v a = *(const float4v*)(src + i);
        float4v b = *(const float4v*)(src + i + 4);
        uint2 pa = pack4(a), pb = pack4(b);
        uint4 o; o.x = pa.x; o.y = pa.y; o.z = pb.x; o.w = pb.y;
        *(uint4*)(dst + i) = o;
        return;
    }
    if (bI < 4616) {              // zero 32 KB rowsum
        const int i = ((bI - 4616) * 256 + threadIdx.x) * 4;
        *(float4v*)(rowsum + i) = float4v{0.f, 0.f, 0.f, 0.f};
        return;
    }
    // transpose-convert: W fp32 [a][e] -> WT bf16 [e][a], 64x64 tiles
    const int z    = (bI - 4616) >> 8;     // 0: Wq, 1: Wk
    const int tile = (bI - 4616) & 255;
    const int ti = tile >> 4;              // a-tile
    const int tj = tile & 15;              // e-tile
    const float* W = z ? Wk : Wq;
    unsigned short* WT = z ? WkT : WqT;
    const int t  = threadIdx.x;
    const int r  = t >> 2;                 // 0..63
    const int c  = (t & 3) << 4;           // 0,16,32,48

    const float* src = W + (size_t)(ti * 64 + r) * EMB + tj * 64 + c;
    #pragma unroll
    for (int u = 0; u < 4; ++u) {
        float4v v = *(const float4v*)(src + 4 * u);
        uint2 p = pack4(v);
        *(uint2*)&T[r][c + 4 * u] = p;
    }
    __syncthreads();
    unsigned short tmp[16];
    #pragma unroll
    for (int u = 0; u < 16; ++u) tmp[u] = T[c + u][r];
    unsigned short* dst = WT + (size_t)(tj * 64 + r) * EMB + ti * 64 + c;
    *(uint4*)(dst)     = *(uint4*)&tmp[0];
    *(uint4*)(dst + 8) = *(uint4*)&tmp[8];
}

// ---- 128x128 core: 3-stage pipeline, BK=32/stage, vmcnt(8), raw barriers ----
static __device__ __forceinline__ void gemm_core(
    const unsigned short* __restrict__ A, const unsigned short* __restrict__ B,
    int lda, int ldb, int m0, int n0, int kend,
    unsigned short* As, unsigned short* Bs, float4v acc[4][4])
{
    const int tid  = threadIdx.x;
    const int r    = tid >> 2;
    const int c8   = (tid & 3) << 3;
    const int lane = tid & 63;
    const int wave = tid >> 6;
    const int quad = lane >> 4;
    const int l16  = lane & 15;
    const int wm   = (wave >> 1) << 6;
    const int wn   = (wave & 1) << 6;

    const unsigned short* Ag = A + (size_t)(m0 + r) * lda + c8;
    const unsigned short* Bg = B + (size_t)(n0 + r) * ldb + c8;
    unsigned short* Al = As + tid * 8;
    unsigned short* Bl = Bs + tid * 8;
    const int niter = kend >> 5;

    #define ISSUE(k0, st) do { \
        unsigned short* al_ = Al + (st) * 4096; \
        unsigned short* bl_ = Bl + (st) * 4096; \
        gload16(Ag + (k0),                    al_); \
        gload16(Ag + (k0) + (size_t)64 * lda, al_ + 2048); \
        gload16(Bg + (k0),                    bl_); \
        gload16(Bg + (k0) + (size_t)64 * ldb, bl_ + 2048); \
    } while (0)

    ISSUE(0, 0);
    ISSUE(32, 1);

    int ci = 0, ii = 2;
    for (int it = 0; it < niter; ++it) {
        const int knext = (it + 2 < niter) ? ((it + 2) << 5) : 0;
        ISSUE(knext, ii);
        asm volatile("s_waitcnt vmcnt(8)" ::: "memory");
        asm volatile("s_barrier" ::: "memory");

        const unsigned short* Ah = As + ci * 4096;
        const unsigned short* Bh = Bs + ci * 4096;
        short8 af[4], bfr[4];
        #pragma unroll
        for (int i = 0; i < 4; ++i)
            af[i] = *(const short8*)&Ah[(wm + 16 * i + l16) * 32 + quad * 8];
        #pragma unroll
        for (int j = 0; j < 4; ++j)
            bfr[j] = *(const short8*)&Bh[(wn + 16 * j + l16) * 32 + quad * 8];
        #pragma unroll
        for (int i = 0; i < 4; ++i)
            #pragma unroll
            for (int j = 0; j < 4; ++j)
                acc[i][j] = __builtin_amdgcn_mfma_f32_16x16x32_bf16(af[i], bfr[j], acc[i][j], 0, 0, 0);

        asm volatile("s_barrier" ::: "memory");
        ci = (ci == 2) ? 0 : ci + 1;
        ii = (ii == 2) ? 0 : ii + 1;
    }
    asm volatile("s_waitcnt vmcnt(0)" ::: "memory");
    #undef ISSUE
}

#define DECL_TILE_IDX() \
    const int lane = threadIdx.x & 63; \
    const int wave = threadIdx.x >> 6; \
    const int quad = lane >> 4; \
    const int l16  = lane & 15; \
    const int wm   = (wave >> 1) << 6; \
    const int wn   = (wave & 1) << 6;

// ---- Mt = (Wq^T Wk)^T * (1/sqrt(A)): gemm(WkT, WqT) contracting over a ----
__global__ __launch_bounds__(256, 3) void m_kernel(
    const unsigned short* __restrict__ WkT, const unsigned short* __restrict__ WqT,
    unsigned short* __restrict__ Mt)
{
    __shared__ __align__(16) unsigned short As[3 * 128 * 32];
    __shared__ __align__(16) unsigned short Bs[3 * 128 * 32];
    const int m0 = (blockIdx.x >> 3) << 7;
    const int n0 = (blockIdx.x & 7) << 7;

    float4v acc[4][4];
    #pragma unroll
    for (int i = 0; i < 4; ++i)
        #pragma unroll
        for (int j = 0; j < 4; ++j)
            acc[i][j] = float4v{0.f, 0.f, 0.f, 0.f};

    gemm_core(WkT, WqT, EMB, EMB, m0, n0, EMB, As, Bs, acc);

    DECL_TILE_IDX();
    const float scale = 0.03125f;  // 1/sqrt(1024), folded here
    #pragma unroll
    for (int i = 0; i < 4; ++i)
        #pragma unroll
        for (int j = 0; j < 4; ++j)
            #pragma unroll
            for (int rr = 0; rr < 4; ++rr) {
                const int row = m0 + wm + 16 * i + quad * 4 + rr;
                const int col = n0 + wn + 16 * j + l16;
                Mt[(size_t)row * EMB + col] = f2bf(acc[i][j][rr] * scale);
            }
}

// ---- qv: 128x256 tiles. 4 waves, wave owns 64x128; 4x8 MFMA grid.
// 3-stage: A 8KB + B 16KB per stage = 72KB LDS -> 2 blocks/CU; VGPR ~200 -> 2 waves/SIMD.
// grid 512 = exactly 2 blocks/CU, zero tail. z=0: Q'=Xb*Mt^T; z=1: V->Vtb transposed. ----
__global__ __launch_bounds__(256, 2) void qv_kernel(
    const unsigned short* __restrict__ Xb, const unsigned short* __restrict__ Mt,
    const unsigned short* __restrict__ Wvb,
    unsigned short* __restrict__ Qpb, unsigned short* __restrict__ Vtb)
{
    __shared__ __align__(16) unsigned short As[3 * 4096];
    __shared__ __align__(16) unsigned short Bs[3 * 8192];
    const int idx   = blockIdx.x;          // 0..511
    const int mlow  = idx & 7;             // XCD swizzle
    const int n0    = ((idx >> 3) & 3) << 8;
    const int mhigh = (idx >> 5) & 7;
    const int z     = idx >> 8;
    const int m0    = ((mhigh << 3) | mlow) << 7;
    const unsigned short* B = (z == 0) ? Mt : Wvb;

    const int tid  = threadIdx.x;
    const int r    = tid >> 2;
    const int c8   = (tid & 3) << 3;
    const int lane = tid & 63;
    const int wave = tid >> 6;
    const int quad = lane >> 4;
    const int l16  = lane & 15;
    const int wm   = (wave >> 1) << 6;
    const int wn   = (wave & 1) << 7;      // 0 or 128

    float4v acc[4][8];
    #pragma unroll
    for (int i = 0; i < 4; ++i)
        #pragma unroll
        for (int j = 0; j < 8; ++j)
            acc[i][j] = float4v{0.f, 0.f, 0.f, 0.f};

    const unsigned short* Ag = Xb + (size_t)(m0 + r) * EMB + c8;
    const unsigned short* Bg = B  + (size_t)(n0 + r) * EMB + c8;
    unsigned short* Al = As + tid * 8;
    unsigned short* Bl = Bs + tid * 8;

    #define ISSUE_W(k0, st) do { \
        unsigned short* al_ = Al + (st) * 4096; \
        unsigned short* bl_ = Bl + (st) * 8192; \
        gload16(Ag + (k0),                     al_); \
        gload16(Ag + (k0) + (size_t)64  * EMB, al_ + 2048); \
        gload16(Bg + (k0),                     bl_); \
        gload16(Bg + (k0) + (size_t)64  * EMB, bl_ + 2048); \
        gload16(Bg + (k0) + (size_t)128 * EMB, bl_ + 4096); \
        gload16(Bg + (k0) + (size_t)192 * EMB, bl_ + 6144); \
    } while (0)

    ISSUE_W(0, 0);
    ISSUE_W(32, 1);

    int ci = 0, ii = 2;
    for (int it = 0; it < 32; ++it) {
        const int knext = (it + 2 < 32) ? ((it + 2) << 5) : 0;
        ISSUE_W(knext, ii);
        asm volatile("s_waitcnt vmcnt(12)" ::: "memory");
        asm volatile("s_barrier" ::: "memory");

        const unsigned short* Ah = As + ci * 4096;
        const unsigned short* Bh = Bs + ci * 8192;
        short8 af[4], bfr[8];
        #pragma unroll
        for (int i = 0; i < 4; ++i)
            af[i] = *(const short8*)&Ah[(wm + 16 * i + l16) * 32 + quad * 8];
        #pragma unroll
        for (int j = 0; j < 8; ++j)
            bfr[j] = *(const short8*)&Bh[(wn + 16 * j + l16) * 32 + quad * 8];
        #pragma unroll
        for (int i = 0; i < 4; ++i)
            #pragma unroll
            for (int j = 0; j < 8; ++j)
                acc[i][j] = __builtin_amdgcn_mfma_f32_16x16x32_bf16(af[i], bfr[j], acc[i][j], 0, 0, 0);

        asm volatile("s_barrier" ::: "memory");
        ci = (ci == 2) ? 0 : ci + 1;
        ii = (ii == 2) ? 0 : ii + 1;
    }
    asm volatile("s_waitcnt vmcnt(0)" ::: "memory");
    #undef ISSUE_W

    #pragma unroll
    for (int i = 0; i < 4; ++i)
        #pragma unroll
        for (int j = 0; j < 8; ++j)
            #pragma unroll
            for (int rr = 0; rr < 4; ++rr) {
                const int row = m0 + wm + 16 * i + quad * 4 + rr;
                const int col = n0 + wn + 16 * j + l16;
                const unsigned short v = f2bf(acc[i][j][rr]);
                if (z == 0) Qpb[(size_t)row * ADIM + col] = v;
                else {
                    const int bb = row >> 11;
                    const int l  = row & (SEQ - 1);
                    Vtb[((size_t)(bb * ADIM + col) << 11) + l] = v;
                }
            }
}

// ---- E = exp(Q' Xb^T) (scale pre-folded into Mt), causal, + rowsum atomics ----
__global__ __launch_bounds__(256, 3) void s_kernel(
    const unsigned short* __restrict__ Qpb, const unsigned short* __restrict__ Xb,
    unsigned short* __restrict__ E, float* __restrict__ rowsum)
{
    const int idx = blockIdx.x;
    const int b   = idx & 3;
    const int tri = idx >> 2;
    int qt = 0;
    while (((qt + 1) * (qt + 2)) / 2 <= tri) ++qt;
    const int kt = tri - (qt * (qt + 1)) / 2;
    const int q0 = qt << 7;
    const int k0 = kt << 7;

    __shared__ __align__(16) unsigned short As[3 * 128 * 32];
    __shared__ __align__(16) unsigned short Bs[3 * 128 * 32];

    float4v acc[4][4];
    #pragma unroll
    for (int i = 0; i < 4; ++i)
        #pragma unroll
        for (int j = 0; j < 4; ++j)
            acc[i][j] = float4v{0.f, 0.f, 0.f, 0.f};

    gemm_core(Qpb + (size_t)b * SEQ * ADIM, Xb + (size_t)b * SEQ * EMB,
              ADIM, EMB, q0, k0, EMB, As, Bs, acc);

    unsigned short* Eb = E + (size_t)b * SEQ * SEQ;
    float* rsb = rowsum + (size_t)b * SEQ;
    DECL_TILE_IDX();
    #pragma unroll
    for (int i = 0; i < 4; ++i)
        #pragma unroll
        for (int rr = 0; rr < 4; ++rr) {
            const int row = q0 + wm + 16 * i + quad * 4 + rr;
            float s = 0.f;
            #pragma unroll
            for (int j = 0; j < 4; ++j) {
                const int col = k0 + wn + 16 * j + l16;
                float e = (col <= row) ? __expf(acc[i][j][rr]) : 0.f;
                s += e;
                Eb[(size_t)row * SEQ + col] = f2bf(e);
            }
            s += __shfl_xor(s, 1);
            s += __shfl_xor(s, 2);
            s += __shfl_xor(s, 4);
            s += __shfl_xor(s, 8);
            if (l16 == 0) atomicAdd(&rsb[row], s);
        }
}

// ---- O = (E V) / rowsum, heavy-first (LPT) ordering, causal K bound ----
__global__ __launch_bounds__(256, 3) void pv_kernel(
    const unsigned short* __restrict__ E, const unsigned short* __restrict__ Vtb,
    const float* __restrict__ rowsum, float* __restrict__ out)
{
    const int idx = blockIdx.x;
    const int t   = 15 - (idx >> 5);
    const int rem = idx & 31;
    const int b   = rem >> 3;
    const int a0  = (rem & 7) << 7;
    const int q0  = t << 7;

    __shared__ __align__(16) unsigned short As[3 * 128 * 32];
    __shared__ __align__(16) unsigned short Bs[3 * 128 * 32];

    float4v acc[4][4];
    #pragma unroll
    for (int i = 0; i < 4; ++i)
        #pragma unroll
        for (int j = 0; j < 4; ++j)
            acc[i][j] = float4v{0.f, 0.f, 0.f, 0.f};

    gemm_core(E + (size_t)b * SEQ * SEQ, Vtb + (size_t)b * ADIM * SEQ,
              SEQ, SEQ, q0, a0, q0 + 128, As, Bs, acc);

    float* ob = out + (size_t)b * SEQ * ADIM;
    const float* rsb = rowsum + (size_t)b * SEQ;
    DECL_TILE_IDX();
    #pragma unroll
    for (int i = 0; i < 4; ++i)
        #pragma unroll
        for (int rr = 0; rr < 4; ++rr) {
            const int row = q0 + wm + 16 * i + quad * 4 + rr;
            const float inv = 1.0f / rsb[row];
            #pragma unroll
            for (int j = 0; j < 4; ++j) {
                const int col = a0 + wn + 16 * j + l16;
                ob[(size_t)row * ADIM + col] = acc[i][j][rr] * inv;
            }
        }
}

extern "C" void kernel_launch(void* const* d_in, const int* in_sizes, int n_in,
                              void* d_out, int out_size, void* d_ws, size_t ws_size,
                              hipStream_t stream)
{
    // setup_inputs order: embedded, W_K, W_Q, W_V
    const float* X  = (const float*)d_in[0];
    const float* Wk = (const float*)d_in[1];
    const float* Wq = (const float*)d_in[2];
    const float* Wv = (const float*)d_in[3];
    float* out = (float*)d_out;

    const size_t MB = 1024 * 1024;
    char* ws = (char*)d_ws;
    unsigned short* Xb  = (unsigned short*)(ws);             // [0,16) MB
    unsigned short* Wvb = (unsigned short*)(ws + 16 * MB);   // [16,18)
    unsigned short* WqT = (unsigned short*)(ws + 18 * MB);   // [18,20)
    unsigned short* WkT = (unsigned short*)(ws + 20 * MB);   // [20,22)
    unsigned short* Mt  = (unsigned short*)(ws + 22 * MB);   // [22,24)
    unsigned short* Qpb = (unsigned short*)(ws + 24 * MB);   // [24,40)
    unsigned short* E   = (unsigned short*)(ws + 40 * MB);   // [40,72)
    unsigned short* Vtb = (unsigned short*)(ws + 72 * MB);   // [72,88)
    float*          rowsum = (float*)(ws + 88 * MB);         // 32 KB

    hipLaunchKernelGGL(prep_kernel, dim3(5128), dim3(256), 0, stream,
                       X, Wv, Wq, Wk, Xb, Wvb, WqT, WkT, rowsum);
    hipLaunchKernelGGL(m_kernel, dim3(64), dim3(256), 0, stream, WkT, WqT, Mt);
    hipLaunchKernelGGL(qv_kernel, dim3(512), dim3(256), 0, stream,
                       Xb, Mt, Wvb, Qpb, Vtb);
    hipLaunchKernelGGL(s_kernel, dim3(4 * 136), dim3(256), 0, stream, Qpb, Xb, E, rowsum);
    hipLaunchKernelGGL(pv_kernel, dim3(512), dim3(256), 0, stream, E, Vtb, rowsum, out);
}

// Round 8
// 228.096 us; speedup vs baseline: 1.1257x; 1.0531x over previous
//
#include <hip/hip_runtime.h>
#include <hip/hip_bf16.h>
#include <stdint.h>

#define BATCH 4
#define SEQ   2048
#define EMB   1024
#define ADIM  1024

typedef __attribute__((ext_vector_type(8))) short  short8;
typedef __attribute__((ext_vector_type(4))) float  float4v;

static __device__ __forceinline__ unsigned short f2bf(float f) {
    unsigned int u = __float_as_uint(f);
    u += 0x7FFFu + ((u >> 16) & 1u);   // RNE (finite inputs)
    return (unsigned short)(u >> 16);
}

static __device__ __forceinline__ uint2 pack4(float4v v) {
    uint2 r;
    r.x = (unsigned)f2bf(v.x) | ((unsigned)f2bf(v.y) << 16);
    r.y = (unsigned)f2bf(v.z) | ((unsigned)f2bf(v.w) << 16);
    return r;
}

// async global->LDS, 16B per lane. LDS dest is wave-uniform base + lane*16.
static __device__ __forceinline__ void gload16(const void* g, void* l) {
    __builtin_amdgcn_global_load_lds(
        (const __attribute__((address_space(1))) void*)g,
        (__attribute__((address_space(3))) void*)l, 16, 0, 0);
}

// ---- fused prep: X->Xb, Wv->Wvb, zero rowsum, transpose-convert Wq/Wk ----
__global__ __launch_bounds__(256) void prep_kernel(
    const float* __restrict__ X,  const float* __restrict__ Wv,
    const float* __restrict__ Wq, const float* __restrict__ Wk,
    unsigned short* __restrict__ Xb, unsigned short* __restrict__ Wvb,
    unsigned short* __restrict__ WqT, unsigned short* __restrict__ WkT,
    float* __restrict__ rowsum)
{
    __shared__ unsigned short T[64][72];
    const int bI = blockIdx.x;
    if (bI < 4608) {              // straight convert
        const float* src; unsigned short* dst; int off;
        if (bI < 4096) { src = X;  dst = Xb;  off = bI; }
        else           { src = Wv; dst = Wvb; off = bI - 4096; }
        const int i = (off * 256 + threadIdx.x) * 8;
        float4v a = *(const float4v*)(src + i);
        float4v b = *(const float4v*)(src + i + 4);
        uint2 pa = pack4(a), pb = pack4(b);
        uint4 o; o.x = pa.x; o.y = pa.y; o.z = pb.x; o.w = pb.y;
        *(uint4*)(dst + i) = o;
        return;
    }
    if (bI < 4616) {              // zero 32 KB rowsum
        const int i = ((bI - 4616) * 256 + threadIdx.x) * 4;
        *(float4v*)(rowsum + i) = float4v{0.f, 0.f, 0.f, 0.f};
        return;
    }
    // transpose-convert: W fp32 [a][e] -> WT bf16 [e][a], 64x64 tiles
    const int z    = (bI - 4616) >> 8;     // 0: Wq, 1: Wk
    const int tile = (bI - 4616) & 255;
    const int ti = tile >> 4;              // a-tile
    const int tj = tile & 15;              // e-tile
    const float* W = z ? Wk : Wq;
    unsigned short* WT = z ? WkT : WqT;
    const int t  = threadIdx.x;
    const int r  = t >> 2;                 // 0..63
    const int c  = (t & 3) << 4;           // 0,16,32,48

    const float* src = W + (size_t)(ti * 64 + r) * EMB + tj * 64 + c;
    #pragma unroll
    for (int u = 0; u < 4; ++u) {
        float4v v = *(const float4v*)(src + 4 * u);
        uint2 p = pack4(v);
        *(uint2*)&T[r][c + 4 * u] = p;
    }
    __syncthreads();
    unsigned short tmp[16];
    #pragma unroll
    for (int u = 0; u < 16; ++u) tmp[u] = T[c + u][r];
    unsigned short* dst = WT + (size_t)(tj * 64 + r) * EMB + ti * 64 + c;
    *(uint4*)(dst)     = *(uint4*)&tmp[0];
    *(uint4*)(dst + 8) = *(uint4*)&tmp[8];
}

// ---- 128x128 core: 3-stage pipeline, BK=32/stage, vmcnt(8), raw barriers ----
static __device__ __forceinline__ void gemm_core(
    const unsigned short* __restrict__ A, const unsigned short* __restrict__ B,
    int lda, int ldb, int m0, int n0, int kend,
    unsigned short* As, unsigned short* Bs, float4v acc[4][4])
{
    const int tid  = threadIdx.x;
    const int r    = tid >> 2;
    const int c8   = (tid & 3) << 3;
    const int lane = tid & 63;
    const int wave = tid >> 6;
    const int quad = lane >> 4;
    const int l16  = lane & 15;
    const int wm   = (wave >> 1) << 6;
    const int wn   = (wave & 1) << 6;

    const unsigned short* Ag = A + (size_t)(m0 + r) * lda + c8;
    const unsigned short* Bg = B + (size_t)(n0 + r) * ldb + c8;
    unsigned short* Al = As + tid * 8;
    unsigned short* Bl = Bs + tid * 8;
    const int niter = kend >> 5;

    #define ISSUE(k0, st) do { \
        unsigned short* al_ = Al + (st) * 4096; \
        unsigned short* bl_ = Bl + (st) * 4096; \
        gload16(Ag + (k0),                    al_); \
        gload16(Ag + (k0) + (size_t)64 * lda, al_ + 2048); \
        gload16(Bg + (k0),                    bl_); \
        gload16(Bg + (k0) + (size_t)64 * ldb, bl_ + 2048); \
    } while (0)

    ISSUE(0, 0);
    ISSUE(32, 1);

    int ci = 0, ii = 2;
    for (int it = 0; it < niter; ++it) {
        const int knext = (it + 2 < niter) ? ((it + 2) << 5) : 0;
        ISSUE(knext, ii);
        asm volatile("s_waitcnt vmcnt(8)" ::: "memory");
        asm volatile("s_barrier" ::: "memory");

        const unsigned short* Ah = As + ci * 4096;
        const unsigned short* Bh = Bs + ci * 4096;
        short8 af[4], bfr[4];
        #pragma unroll
        for (int i = 0; i < 4; ++i)
            af[i] = *(const short8*)&Ah[(wm + 16 * i + l16) * 32 + quad * 8];
        #pragma unroll
        for (int j = 0; j < 4; ++j)
            bfr[j] = *(const short8*)&Bh[(wn + 16 * j + l16) * 32 + quad * 8];
        #pragma unroll
        for (int i = 0; i < 4; ++i)
            #pragma unroll
            for (int j = 0; j < 4; ++j)
                acc[i][j] = __builtin_amdgcn_mfma_f32_16x16x32_bf16(af[i], bfr[j], acc[i][j], 0, 0, 0);

        asm volatile("s_barrier" ::: "memory");
        ci = (ci == 2) ? 0 : ci + 1;
        ii = (ii == 2) ? 0 : ii + 1;
    }
    asm volatile("s_waitcnt vmcnt(0)" ::: "memory");
    #undef ISSUE
}

#define DECL_TILE_IDX() \
    const int lane = threadIdx.x & 63; \
    const int wave = threadIdx.x >> 6; \
    const int quad = lane >> 4; \
    const int l16  = lane & 15; \
    const int wm   = (wave >> 1) << 6; \
    const int wn   = (wave & 1) << 6;

// ---- Mt = (Wq^T Wk)^T * (1/sqrt(A)): gemm(WkT, WqT) contracting over a ----
__global__ __launch_bounds__(256, 3) void m_kernel(
    const unsigned short* __restrict__ WkT, const unsigned short* __restrict__ WqT,
    unsigned short* __restrict__ Mt)
{
    __shared__ __align__(16) unsigned short As[3 * 128 * 32];
    __shared__ __align__(16) unsigned short Bs[3 * 128 * 32];
    const int m0 = (blockIdx.x >> 3) << 7;
    const int n0 = (blockIdx.x & 7) << 7;

    float4v acc[4][4];
    #pragma unroll
    for (int i = 0; i < 4; ++i)
        #pragma unroll
        for (int j = 0; j < 4; ++j)
            acc[i][j] = float4v{0.f, 0.f, 0.f, 0.f};

    gemm_core(WkT, WqT, EMB, EMB, m0, n0, EMB, As, Bs, acc);

    DECL_TILE_IDX();
    const float scale = 0.03125f;  // 1/sqrt(1024), folded here
    #pragma unroll
    for (int i = 0; i < 4; ++i)
        #pragma unroll
        for (int j = 0; j < 4; ++j)
            #pragma unroll
            for (int rr = 0; rr < 4; ++rr) {
                const int row = m0 + wm + 16 * i + quad * 4 + rr;
                const int col = n0 + wn + 16 * j + l16;
                Mt[(size_t)row * EMB + col] = f2bf(acc[i][j][rr] * scale);
            }
}

// ---- qv: 128x256 tiles, 4x8 MFMA grid per wave-quadrant (64x128).
// z=0: Q'=Xb*Mt^T (direct store); z=1: V -> Vtb via LDS transpose (coalesced). ----
__global__ __launch_bounds__(256, 2) void qv_kernel(
    const unsigned short* __restrict__ Xb, const unsigned short* __restrict__ Mt,
    const unsigned short* __restrict__ Wvb,
    unsigned short* __restrict__ Qpb, unsigned short* __restrict__ Vtb)
{
    __shared__ __align__(16) unsigned short LDS[3 * 4096 + 3 * 8192]; // 73728 B
    unsigned short* As = LDS;
    unsigned short* Bs = LDS + 3 * 4096;
    const int idx   = blockIdx.x;          // 0..511
    const int mlow  = idx & 7;             // XCD swizzle
    const int n0    = ((idx >> 3) & 3) << 8;
    const int mhigh = (idx >> 5) & 7;
    const int z     = idx >> 8;
    const int m0    = ((mhigh << 3) | mlow) << 7;
    const unsigned short* B = (z == 0) ? Mt : Wvb;

    const int tid  = threadIdx.x;
    const int r    = tid >> 2;
    const int c8   = (tid & 3) << 3;
    const int lane = tid & 63;
    const int wave = tid >> 6;
    const int quad = lane >> 4;
    const int l16  = lane & 15;
    const int wm   = (wave >> 1) << 6;
    const int wn   = (wave & 1) << 7;      // 0 or 128

    float4v acc[4][8];
    #pragma unroll
    for (int i = 0; i < 4; ++i)
        #pragma unroll
        for (int j = 0; j < 8; ++j)
            acc[i][j] = float4v{0.f, 0.f, 0.f, 0.f};

    const unsigned short* Ag = Xb + (size_t)(m0 + r) * EMB + c8;
    const unsigned short* Bg = B  + (size_t)(n0 + r) * EMB + c8;
    unsigned short* Al = As + tid * 8;
    unsigned short* Bl = Bs + tid * 8;

    #define ISSUE_W(k0, st) do { \
        unsigned short* al_ = Al + (st) * 4096; \
        unsigned short* bl_ = Bl + (st) * 8192; \
        gload16(Ag + (k0),                     al_); \
        gload16(Ag + (k0) + (size_t)64  * EMB, al_ + 2048); \
        gload16(Bg + (k0),                     bl_); \
        gload16(Bg + (k0) + (size_t)64  * EMB, bl_ + 2048); \
        gload16(Bg + (k0) + (size_t)128 * EMB, bl_ + 4096); \
        gload16(Bg + (k0) + (size_t)192 * EMB, bl_ + 6144); \
    } while (0)

    ISSUE_W(0, 0);
    ISSUE_W(32, 1);

    int ci = 0, ii = 2;
    for (int it = 0; it < 32; ++it) {
        const int knext = (it + 2 < 32) ? ((it + 2) << 5) : 0;
        ISSUE_W(knext, ii);
        asm volatile("s_waitcnt vmcnt(12)" ::: "memory");
        asm volatile("s_barrier" ::: "memory");

        const unsigned short* Ah = As + ci * 4096;
        const unsigned short* Bh = Bs + ci * 8192;
        short8 af[4], bfr[8];
        #pragma unroll
        for (int i = 0; i < 4; ++i)
            af[i] = *(const short8*)&Ah[(wm + 16 * i + l16) * 32 + quad * 8];
        #pragma unroll
        for (int j = 0; j < 8; ++j)
            bfr[j] = *(const short8*)&Bh[(wn + 16 * j + l16) * 32 + quad * 8];
        #pragma unroll
        for (int i = 0; i < 4; ++i)
            #pragma unroll
            for (int j = 0; j < 8; ++j)
                acc[i][j] = __builtin_amdgcn_mfma_f32_16x16x32_bf16(af[i], bfr[j], acc[i][j], 0, 0, 0);

        asm volatile("s_barrier" ::: "memory");
        ci = (ci == 2) ? 0 : ci + 1;
        ii = (ii == 2) ? 0 : ii + 1;
    }
    asm volatile("s_waitcnt vmcnt(0)" ::: "memory");
    #undef ISSUE_W

    if (z == 0) {
        #pragma unroll
        for (int i = 0; i < 4; ++i)
            #pragma unroll
            for (int j = 0; j < 8; ++j)
                #pragma unroll
                for (int rr = 0; rr < 4; ++rr) {
                    const int row = m0 + wm + 16 * i + quad * 4 + rr;
                    const int col = n0 + wn + 16 * j + l16;
                    Qpb[(size_t)row * ADIM + col] = f2bf(acc[i][j][rr]);
                }
    } else {
        // LDS transpose: T[acol][q] with q-stride 136 (272B rows, 16B aligned)
        __syncthreads();
        unsigned short* T = LDS;   // 256*136 = 34816 shorts <= 36864
        #pragma unroll
        for (int i = 0; i < 4; ++i)
            #pragma unroll
            for (int j = 0; j < 8; ++j) {
                const int qrow = wm + 16 * i + quad * 4;     // 4-aligned
                const int acol = wn + 16 * j + l16;
                uint2 w;
                w.x = (unsigned)f2bf(acc[i][j][0]) | ((unsigned)f2bf(acc[i][j][1]) << 16);
                w.y = (unsigned)f2bf(acc[i][j][2]) | ((unsigned)f2bf(acc[i][j][3]) << 16);
                *(uint2*)&T[acol * 136 + qrow] = w;          // 8B store, 8B-aligned
            }
        __syncthreads();
        // thread tid owns a-col tid: 128 contiguous q entries -> 256B burst
        const int bb = m0 >> 11;
        const int l0 = m0 & (SEQ - 1);
        unsigned short* dst = Vtb + (((size_t)(bb * ADIM + n0 + tid)) << 11) + l0;
        #pragma unroll
        for (int u = 0; u < 16; ++u)
            *(uint4*)(dst + u * 8) = *(const uint4*)&T[tid * 136 + u * 8];
    }
}

// ---- E = exp(Q' Xb^T) (scale pre-folded into Mt), causal, + rowsum atomics ----
__global__ __launch_bounds__(256, 3) void s_kernel(
    const unsigned short* __restrict__ Qpb, const unsigned short* __restrict__ Xb,
    unsigned short* __restrict__ E, float* __restrict__ rowsum)
{
    const int idx = blockIdx.x;
    const int b   = idx & 3;
    const int tri = idx >> 2;
    int qt = 0;
    while (((qt + 1) * (qt + 2)) / 2 <= tri) ++qt;
    const int kt = tri - (qt * (qt + 1)) / 2;
    const int q0 = qt << 7;
    const int k0 = kt << 7;

    __shared__ __align__(16) unsigned short As[3 * 128 * 32];
    __shared__ __align__(16) unsigned short Bs[3 * 128 * 32];

    float4v acc[4][4];
    #pragma unroll
    for (int i = 0; i < 4; ++i)
        #pragma unroll
        for (int j = 0; j < 4; ++j)
            acc[i][j] = float4v{0.f, 0.f, 0.f, 0.f};

    gemm_core(Qpb + (size_t)b * SEQ * ADIM, Xb + (size_t)b * SEQ * EMB,
              ADIM, EMB, q0, k0, EMB, As, Bs, acc);

    unsigned short* Eb = E + (size_t)b * SEQ * SEQ;
    float* rsb = rowsum + (size_t)b * SEQ;
    DECL_TILE_IDX();
    #pragma unroll
    for (int i = 0; i < 4; ++i)
        #pragma unroll
        for (int rr = 0; rr < 4; ++rr) {
            const int row = q0 + wm + 16 * i + quad * 4 + rr;
            float s = 0.f;
            #pragma unroll
            for (int j = 0; j < 4; ++j) {
                const int col = k0 + wn + 16 * j + l16;
                float e = (col <= row) ? __expf(acc[i][j][rr]) : 0.f;
                s += e;
                Eb[(size_t)row * SEQ + col] = f2bf(e);
            }
            s += __shfl_xor(s, 1);
            s += __shfl_xor(s, 2);
            s += __shfl_xor(s, 4);
            s += __shfl_xor(s, 8);
            if (l16 == 0) atomicAdd(&rsb[row], s);
        }
}

// ---- O = (E V) / rowsum. Balanced pairing: blocks c and c+256 land on the
// same CU (round-robin %8 XCD, /8 %32 CU both match) and their t sum to 15,
// so every CU carries a constant 17 t-units. ----
__global__ __launch_bounds__(256, 3) void pv_kernel(
    const unsigned short* __restrict__ E, const unsigned short* __restrict__ Vtb,
    const float* __restrict__ rowsum, float* __restrict__ out)
{
    const int idx = blockIdx.x;
    const int t   = (idx < 256) ? (15 - (idx >> 5)) : ((idx - 256) >> 5);
    const int rem = idx & 31;
    const int b   = rem >> 3;
    const int a0  = (rem & 7) << 7;
    const int q0  = t << 7;

    __shared__ __align__(16) unsigned short As[3 * 128 * 32];
    __shared__ __align__(16) unsigned short Bs[3 * 128 * 32];

    float4v acc[4][4];
    #pragma unroll
    for (int i = 0; i < 4; ++i)
        #pragma unroll
        for (int j = 0; j < 4; ++j)
            acc[i][j] = float4v{0.f, 0.f, 0.f, 0.f};

    gemm_core(E + (size_t)b * SEQ * SEQ, Vtb + (size_t)b * ADIM * SEQ,
              SEQ, SEQ, q0, a0, q0 + 128, As, Bs, acc);

    float* ob = out + (size_t)b * SEQ * ADIM;
    const float* rsb = rowsum + (size_t)b * SEQ;
    DECL_TILE_IDX();
    #pragma unroll
    for (int i = 0; i < 4; ++i)
        #pragma unroll
        for (int rr = 0; rr < 4; ++rr) {
            const int row = q0 + wm + 16 * i + quad * 4 + rr;
            const float inv = 1.0f / rsb[row];
            #pragma unroll
            for (int j = 0; j < 4; ++j) {
                const int col = a0 + wn + 16 * j + l16;
                ob[(size_t)row * ADIM + col] = acc[i][j][rr] * inv;
            }
        }
}

extern "C" void kernel_launch(void* const* d_in, const int* in_sizes, int n_in,
                              void* d_out, int out_size, void* d_ws, size_t ws_size,
                              hipStream_t stream)
{
    // setup_inputs order: embedded, W_K, W_Q, W_V
    const float* X  = (const float*)d_in[0];
    const float* Wk = (const float*)d_in[1];
    const float* Wq = (const float*)d_in[2];
    const float* Wv = (const float*)d_in[3];
    float* out = (float*)d_out;

    const size_t MB = 1024 * 1024;
    char* ws = (char*)d_ws;
    unsigned short* Xb  = (unsigned short*)(ws);             // [0,16) MB
    unsigned short* Wvb = (unsigned short*)(ws + 16 * MB);   // [16,18)
    unsigned short* WqT = (unsigned short*)(ws + 18 * MB);   // [18,20)
    unsigned short* WkT = (unsigned short*)(ws + 20 * MB);   // [20,22)
    unsigned short* Mt  = (unsigned short*)(ws + 22 * MB);   // [22,24)
    unsigned short* Qpb = (unsigned short*)(ws + 24 * MB);   // [24,40)
    unsigned short* E   = (unsigned short*)(ws + 40 * MB);   // [40,72)
    unsigned short* Vtb = (unsigned short*)(ws + 72 * MB);   // [72,88)
    float*          rowsum = (float*)(ws + 88 * MB);         // 32 KB

    hipLaunchKernelGGL(prep_kernel, dim3(5128), dim3(256), 0, stream,
                       X, Wv, Wq, Wk, Xb, Wvb, WqT, WkT, rowsum);
    hipLaunchKernelGGL(m_kernel, dim3(64), dim3(256), 0, stream, WkT, WqT, Mt);
    hipLaunchKernelGGL(qv_kernel, dim3(512), dim3(256), 0, stream,
                       Xb, Mt, Wvb, Qpb, Vtb);
    hipLaunchKernelGGL(s_kernel, dim3(4 * 136), dim3(256), 0, stream, Qpb, Xb, E, rowsum);
    hipLaunchKernelGGL(pv_kernel, dim3(512), dim3(256), 0, stream, E, Vtb, rowsum, out);
}